// Round 13
// baseline (1448.593 us; speedup 1.0000x reference)
//
#include <hip/hip_runtime.h>
#include <hip/hip_bf16.h>
#include <stdint.h>

typedef __hip_bfloat16 bf16;
typedef unsigned short ushort_t;
typedef __attribute__((ext_vector_type(8))) short bf16x8;
typedef __attribute__((ext_vector_type(4))) float f32x4;

#define EPSV 1.1920929e-07f

__device__ __forceinline__ float bfu2f(uint32_t u) {
  union { uint32_t i; float f; } t; t.i = u << 16; return t.f;
}
__device__ __forceinline__ ushort_t f2bfu(float f) {
  bf16 h = __float2bfloat16(f);
  return *reinterpret_cast<ushort_t*>(&h);
}

#define BAR() __builtin_amdgcn_s_barrier()
#define SCHEDB() __builtin_amdgcn_sched_barrier(0)
#define WAIT_LGKM0() { asm volatile("s_waitcnt lgkmcnt(0)" ::: "memory"); SCHEDB(); }
#define WAIT_VM4() asm volatile("s_waitcnt vmcnt(4)" ::: "memory")
#define WAIT_VM0() asm volatile("s_waitcnt vmcnt(0)" ::: "memory")

// ---------------- prep_all: weight transposes + rope tables + embed+RMS ----------------
__global__ __launch_bounds__(256) void prep_all_kernel(
    const int* __restrict__ ids, const float* __restrict__ emb,
    const float* __restrict__ norm1w0,
    const float* __restrict__ wq, const float* __restrict__ wk,
    const float* __restrict__ wv, const float* __restrict__ wo,
    const float* __restrict__ wg, const float* __restrict__ wvl,
    const float* __restrict__ wout, const float* __restrict__ unemb,
    float* __restrict__ cosT, float* __restrict__ sinT,
    bf16* __restrict__ wqkvT, bf16* __restrict__ woT,
    bf16* __restrict__ wgvT, bf16* __restrict__ woutT,
    bf16* __restrict__ unembT,
    float* __restrict__ x, bf16* __restrict__ h) {
  int id = blockIdx.x;
  __shared__ float tl[32][33];
  __shared__ float red[4];

  if (id >= 65536) {
    const int row = id - 65536;
    const int tid = threadIdx.x;
    const float* er = emb + (size_t)ids[row] * 768;
    float v0 = er[tid], v1 = er[tid + 256], v2 = er[tid + 512];
    float s = v0 * v0 + v1 * v1 + v2 * v2;
#pragma unroll
    for (int d = 1; d < 64; d <<= 1) s += __shfl_xor(s, d);
    if ((tid & 63) == 0) red[tid >> 6] = s;
    __syncthreads();
    s = red[0] + red[1] + red[2] + red[3];
    float rs = rsqrtf(s * (1.0f / 768.0f) + EPSV);
    float* xr = x + (size_t)row * 768;
    bf16* hr = h + (size_t)row * 768;
    xr[tid] = v0; xr[tid + 256] = v1; xr[tid + 512] = v2;
    hr[tid]       = __float2bfloat16(v0 * rs * norm1w0[tid]);
    hr[tid + 256] = __float2bfloat16(v1 * rs * norm1w0[tid + 256]);
    hr[tid + 512] = __float2bfloat16(v2 * rs * norm1w0[tid + 512]);
    return;
  }
  if (id >= 65472) {
    int i = (id - 65472) * 256 + threadIdx.x;
    int c = i >> 5, dp = i & 31;
    float inv = powf(10000.0f, -(2.0f * dp) / 64.0f);
    float a = (float)c * inv;
    cosT[i] = cosf(a);
    sinT[i] = sinf(a);
    return;
  }

  const float* src; bf16* dst; int K, N, tile;
  bool gvmode = false; int w2 = 0;
  if (id < 13824) {
    int m = id / 576; tile = id % 576;
    int l = m >> 2, w3 = m & 3;
    K = 768; N = 768;
    const float* s0 = (w3 == 0) ? wq : (w3 == 1) ? wk : (w3 == 2) ? wv : wo;
    src = s0 + (size_t)l * 768 * 768;
    dst = (w3 < 3) ? wqkvT + (size_t)l * 2304 * 768 + (size_t)w3 * 768 * 768
                   : woT + (size_t)l * 768 * 768;
  } else if (id < 32256) {
    int id2 = id - 13824; int m = id2 / 1536; tile = id2 % 1536;
    int l = m >> 1; w2 = m & 1;
    K = 768; N = 2048; gvmode = true;
    src = (w2 ? wvl : wg) + (size_t)l * 768 * 2048;
    dst = wgvT + (size_t)l * 4096 * 768;
  } else if (id < 41472) {
    int id2 = id - 32256; int l = id2 / 1536; tile = id2 % 1536;
    K = 2048; N = 768;
    src = wout + (size_t)l * 2048 * 768;
    dst = woutT + (size_t)l * 768 * 2048;
  } else {
    tile = id - 41472;
    K = 768; N = 32000;
    src = unemb; dst = unembT;
  }
  int ntn = N >> 5;
  int nt = (tile % ntn) << 5, kt = (tile / ntn) << 5;
  int tx = threadIdx.x & 31, ty = threadIdx.x >> 5;
#pragma unroll
  for (int i = 0; i < 4; ++i)
    tl[ty + i * 8][tx] = src[(size_t)(kt + ty + i * 8) * N + nt + tx];
  __syncthreads();
#pragma unroll
  for (int i = 0; i < 4; ++i) {
    int n = nt + ty + i * 8;
    size_t nrow = gvmode ? (size_t)((n >> 7) * 256 + w2 * 128 + (n & 127)) : (size_t)n;
    dst[nrow * K + kt + tx] = __float2bfloat16(tl[tx][ty + i * 8]);
  }
}

// ---------------- fused split-K reduce (bf16 partials) + residual + RMSNorm ----------------
template <int S>
__global__ __launch_bounds__(256) void reduce_rms_kernel(float* __restrict__ x,
                                                         const bf16* __restrict__ P,
                                                         const float* __restrict__ wgt,
                                                         bf16* __restrict__ h) {
  const int row = blockIdx.x;
  const int tid = threadIdx.x;
  float* xr = x + (size_t)row * 768;
  const bool act2 = tid < 128;
  const int u0 = tid, u1 = tid + 256;

  float v00, v01, v10 = 0.f, v11 = 0.f;
  float s;
  {
    float2 xv = *(const float2*)(xr + 2 * u0);
    float a0 = xv.x, a1 = xv.y;
#pragma unroll
    for (int z = 0; z < S; ++z) {
      uint32_t pu = *(const uint32_t*)(P + ((size_t)z * 4096 + row) * 768 + 2 * u0);
      a0 += bfu2f(pu & 0xffffu); a1 += bfu2f(pu >> 16);
    }
    v00 = a0; v01 = a1;
    s = a0 * a0 + a1 * a1;
  }
  if (act2) {
    float2 xv = *(const float2*)(xr + 2 * u1);
    float a0 = xv.x, a1 = xv.y;
#pragma unroll
    for (int z = 0; z < S; ++z) {
      uint32_t pu = *(const uint32_t*)(P + ((size_t)z * 4096 + row) * 768 + 2 * u1);
      a0 += bfu2f(pu & 0xffffu); a1 += bfu2f(pu >> 16);
    }
    v10 = a0; v11 = a1;
    s += a0 * a0 + a1 * a1;
  }
#pragma unroll
  for (int d = 1; d < 64; d <<= 1) s += __shfl_xor(s, d);
  __shared__ float red[4];
  if ((tid & 63) == 0) red[tid >> 6] = s;
  __syncthreads();
  s = red[0] + red[1] + red[2] + red[3];
  float rs = rsqrtf(s * (1.0f / 768.0f) + EPSV);
  bf16* hr = h + (size_t)row * 768;
  {
    *(float2*)(xr + 2 * u0) = make_float2(v00, v01);
    uint32_t hw = (uint32_t)f2bfu(v00 * rs * wgt[2 * u0]) |
                  ((uint32_t)f2bfu(v01 * rs * wgt[2 * u0 + 1]) << 16);
    *(uint32_t*)(hr + 2 * u0) = hw;
  }
  if (act2) {
    *(float2*)(xr + 2 * u1) = make_float2(v10, v11);
    uint32_t hw = (uint32_t)f2bfu(v10 * rs * wgt[2 * u1]) |
                  ((uint32_t)f2bfu(v11 * rs * wgt[2 * u1 + 1]) << 16);
    *(uint32_t*)(hr + 2 * u1) = hw;
  }
}

// ---------------- 128^2 split-K GEMM: P[z][M][N](bf16) = A[:,zKS:(z+1)KS] * BT^T ----------------
__global__ __launch_bounds__(256) void gemm_bt_sk(const bf16* __restrict__ A,
                                                  const bf16* __restrict__ BT,
                                                  bf16* __restrict__ P,
                                                  int M, int N, int KS, int K) {
  __shared__ __align__(16) bf16 As[128 * 32];
  __shared__ __align__(16) bf16 Bs[128 * 32];
  const int tid = threadIdx.x;
  const int lane = tid & 63, w = tid >> 6;
  const int g = lane >> 4, lc = lane & 15;
  const int bm = blockIdx.y * 128, bn = blockIdx.x * 128;
  const int z = blockIdx.z;
  const int koff = z * KS;
  const int wm = (w >> 1) * 64, wn = (w & 1) * 64;

  f32x4 acc[4][4];
#pragma unroll
  for (int i = 0; i < 4; ++i)
#pragma unroll
    for (int j = 0; j < 4; ++j) acc[i][j] = (f32x4){0.f, 0.f, 0.f, 0.f};

  for (int k0 = koff; k0 < koff + KS; k0 += 32) {
    __syncthreads();
#pragma unroll
    for (int j = 0; j < 2; ++j) {
      int c = (w * 2 + j) * 64 + lane;
      int row = c >> 2, part = c & 3;
      const bf16* srcA = A + (size_t)(bm + row) * K + k0 + part * 8;
      const bf16* srcB = BT + (size_t)(bn + row) * K + k0 + part * 8;
      __builtin_amdgcn_global_load_lds((const __attribute__((address_space(1))) void*)srcA,
                                       (__attribute__((address_space(3))) void*)(As + (w * 2 + j) * 512),
                                       16, 0, 0);
      __builtin_amdgcn_global_load_lds((const __attribute__((address_space(1))) void*)srcB,
                                       (__attribute__((address_space(3))) void*)(Bs + (w * 2 + j) * 512),
                                       16, 0, 0);
    }
    __syncthreads();
    bf16x8 af[4], bfr[4];
#pragma unroll
    for (int mi = 0; mi < 4; ++mi)
      af[mi] = *(const bf16x8*)(As + (wm + mi * 16 + lc) * 32 + g * 8);
#pragma unroll
    for (int ni = 0; ni < 4; ++ni)
      bfr[ni] = *(const bf16x8*)(Bs + (wn + ni * 16 + lc) * 32 + g * 8);
#pragma unroll
    for (int mi = 0; mi < 4; ++mi)
#pragma unroll
      for (int ni = 0; ni < 4; ++ni)
        acc[mi][ni] = __builtin_amdgcn_mfma_f32_16x16x32_bf16(af[mi], bfr[ni], acc[mi][ni], 0, 0, 0);
  }

  bf16* Pz = P + (size_t)z * M * N;
#pragma unroll
  for (int mi = 0; mi < 4; ++mi)
#pragma unroll
    for (int ni = 0; ni < 4; ++ni)
#pragma unroll
      for (int r = 0; r < 4; ++r) {
        size_t row = (size_t)bm + wm + mi * 16 + g * 4 + r;
        size_t col = (size_t)bn + wn + ni * 16 + lc;
        Pz[row * N + col] = __float2bfloat16(acc[mi][ni][r]);
      }
}

// ---------------- 256^2 8-phase GEMM (T2+T3+T4+T5) ----------------
// MODE 0: store bf16 ; MODE 1: store f32 ; MODE 3: SWIGLU ; MODE 4: bf16 + RoPE
template <int MODE>
__global__ __launch_bounds__(512, 2) void gemm256(const bf16* __restrict__ A,
                                                  const bf16* __restrict__ BT,
                                                  void* __restrict__ C,
                                                  int M, int N, int K,
                                                  const float* __restrict__ cosT,
                                                  const float* __restrict__ sinT) {
  __shared__ __align__(16) bf16 lds[2][4][256 * 32];

  const int tid = threadIdx.x;
  const int lane = tid & 63, w = tid >> 6;
  const int wr = w >> 2, wc = w & 3;
  const int g = lane >> 4, lc = lane & 15;

  const int nwg = gridDim.x;
  const int q = nwg >> 3;
  const int wg = ((int)blockIdx.x & 7) * q + ((int)blockIdx.x >> 3);
  const int nby = M >> 8;
  const int bx = wg / nby, by = wg % nby;
  const int bm = by << 8, bn = bx << 8;

  const bf16* Ap = A + (size_t)bm * K;
  const bf16* Bp = BT + (size_t)bn * K;

  const int soff = (lc * 64) + ((((lane >> 4) ^ ((lane >> 1) & 3)) << 4));

  auto stage_half = [&](int buf, int slab, const bf16* Base, int kcol) {
#pragma unroll
    for (int j = 0; j < 2; ++j) {
      int half_id = w * 2 + j;
      int row = half_id * 16 + (lane >> 2);
      int s_log = (lane & 3) ^ ((lane >> 3) & 3);
      const bf16* src = Base + (size_t)row * K + kcol + s_log * 8;
      bf16* dst = &lds[buf][slab][half_id * 512];
      __builtin_amdgcn_global_load_lds((const __attribute__((address_space(1))) void*)src,
                                       (__attribute__((address_space(3))) void*)dst,
                                       16, 0, 0);
    }
  };

  f32x4 acc[8][4];
#pragma unroll
  for (int i = 0; i < 8; ++i)
#pragma unroll
    for (int j = 0; j < 4; ++j) acc[i][j] = (f32x4){0.f, 0.f, 0.f, 0.f};

  const int NT = K >> 6;

  stage_half(0, 0, Ap, 0);
  stage_half(0, 1, Bp, 0);
  stage_half(0, 2, Ap, 32);
  stage_half(0, 3, Bp, 32);

  bf16x8 aF[4], bF[4];

  auto ds_A = [&](int buf, int kk, int mh) {
#pragma unroll
    for (int i = 0; i < 4; ++i) {
      int byte = (wr * 128 + mh * 64 + i * 16) * 64 + soff;
      aF[i] = *(const bf16x8*)((const char*)&lds[buf][kk * 2][0] + byte);
    }
  };
  auto ds_B = [&](int buf, int kk) {
#pragma unroll
    for (int nf = 0; nf < 4; ++nf) {
      int rb = (MODE == 3) ? ((nf < 2) ? (wc * 32 + nf * 16) : (128 + wc * 32 + (nf - 2) * 16))
                           : (wc * 64 + nf * 16);
      int byte = rb * 64 + soff;
      bF[nf] = *(const bf16x8*)((const char*)&lds[buf][kk * 2 + 1][0] + byte);
    }
  };
  auto mfma16 = [&](int mh) {
    __builtin_amdgcn_s_setprio(1);
#pragma unroll
    for (int i = 0; i < 4; ++i)
#pragma unroll
      for (int nf = 0; nf < 4; ++nf)
        acc[mh * 4 + i][nf] =
            __builtin_amdgcn_mfma_f32_16x16x32_bf16(aF[i], bF[nf], acc[mh * 4 + i][nf], 0, 0, 0);
    __builtin_amdgcn_s_setprio(0);
  };

  for (int t = 0; t < NT; ++t) {
    const int buf = t & 1;
    const bool pf = (t + 1) < NT;
    const int knext = (t + 1) << 6;

    WAIT_VM4();
    BAR(); SCHEDB();
    if (pf) stage_half(buf ^ 1, 0, Ap, knext);
    ds_A(buf, 0, 0);
    ds_B(buf, 0);
    BAR();
    WAIT_LGKM0();
    mfma16(0);

    if (pf) stage_half(buf ^ 1, 1, Bp, knext);
    ds_A(buf, 0, 1);
    BAR();
    WAIT_LGKM0();
    mfma16(1);

    if (pf) { WAIT_VM4(); } else { WAIT_VM0(); }
    BAR(); SCHEDB();
    if (pf) stage_half(buf ^ 1, 2, Ap, knext + 32);
    ds_A(buf, 1, 0);
    ds_B(buf, 1);
    BAR();
    WAIT_LGKM0();
    mfma16(0);

    if (pf) stage_half(buf ^ 1, 3, Bp, knext + 32);
    ds_A(buf, 1, 1);
    BAR();
    WAIT_LGKM0();
    mfma16(1);
  }

  if (MODE == 3) {
    bf16* act = (bf16*)C;
#pragma unroll
    for (int mf = 0; mf < 8; ++mf)
#pragma unroll
      for (int nf = 0; nf < 2; ++nf)
#pragma unroll
        for (int r = 0; r < 4; ++r) {
          size_t row = (size_t)bm + wr * 128 + mf * 16 + g * 4 + r;
          size_t col = (size_t)(bn >> 1) + wc * 32 + nf * 16 + lc;
          float gg = acc[mf][nf][r];
          float vv = acc[mf][nf + 2][r];
          float sg = gg / (1.0f + __expf(-gg));
          act[row * 2048 + col] = __float2bfloat16(sg * vv);
        }
  } else if (MODE == 4) {
#pragma unroll
    for (int mf = 0; mf < 8; ++mf)
#pragma unroll
      for (int nf = 0; nf < 4; ++nf)
#pragma unroll
        for (int r = 0; r < 4; ++r) {
          int row = bm + wr * 128 + mf * 16 + g * 4 + r;
          int col = bn + wc * 64 + nf * 16 + lc;
          float v = acc[mf][nf][r];
          float p = __shfl_xor(v, 1);
          float outv = v;
          if (col < 1536) {
            int cpos = row & 511;
            int dp = (col & 63) >> 1;
            float cs = cosT[cpos * 32 + dp], sn = sinT[cpos * 32 + dp];
            float o = (col & 1) ? (p * sn + v * cs) : (v * cs - p * sn);
            outv = (col < 768) ? o * 0.125f : o;
          }
          ((bf16*)C)[(size_t)row * N + col] = __float2bfloat16(outv);
        }
  } else {
#pragma unroll
    for (int mf = 0; mf < 8; ++mf)
#pragma unroll
      for (int nf = 0; nf < 4; ++nf)
#pragma unroll
        for (int r = 0; r < 4; ++r) {
          size_t row = (size_t)bm + wr * 128 + mf * 16 + g * 4 + r;
          size_t col = (size_t)bn + wc * 64 + nf * 16 + lc;
          float v = acc[mf][nf][r];
          if (MODE == 0) ((bf16*)C)[row * N + col] = __float2bfloat16(v);
          else           ((float*)C)[row * N + col] = v;
        }
  }
}

// ---------------- fused causal flash attention (q,k pre-roped) ----------------
// round-8/12 structure; longest-first scheduling (qt = 3 - blockIdx.x) + T5 setprio.
__global__ __launch_bounds__(256) void attn_kernel(const bf16* __restrict__ qkv,
                                                   bf16* __restrict__ out) {
  const int qt = 3 - blockIdx.x;   // heavy blocks (more k-tiles) dispatch first
  const int h  = blockIdx.y;
  const int b  = blockIdx.z;
  const int tid = threadIdx.x;
  const int lane = tid & 63, w = tid >> 6;
  const int g = lane >> 4, lc = lane & 15;

  __shared__ __align__(16) bf16 Ks[64][72];
  __shared__ __align__(16) bf16 Vt[64][72];
  __shared__ __align__(16) bf16 Pl[4][32][72];

  bf16x8 qa[2][2];
#pragma unroll
  for (int mi = 0; mi < 2; ++mi)
#pragma unroll
    for (int ks = 0; ks < 2; ++ks) {
      size_t t = (size_t)b * 512 + qt * 128 + w * 32 + mi * 16 + lc;
      qa[mi][ks] = *(const bf16x8*)(qkv + t * 2304 + h * 64 + ks * 32 + g * 8);
    }

  float m_r[2][4], l_r[2][4];
  f32x4 acc_o[2][4];
#pragma unroll
  for (int mi = 0; mi < 2; ++mi)
#pragma unroll
    for (int r = 0; r < 4; ++r) { m_r[mi][r] = -1e30f; l_r[mi][r] = 0.f; }
#pragma unroll
  for (int mi = 0; mi < 2; ++mi)
#pragma unroll
    for (int ni = 0; ni < 4; ++ni) acc_o[mi][ni] = (f32x4){0.f, 0.f, 0.f, 0.f};

  const int nkt = 2 * qt + 2;
  for (int kt = 0; kt < nkt; ++kt) {
    __syncthreads();
    // K: vectorized 16B copy
#pragma unroll
    for (int j = 0; j < 2; ++j) {
      int u = j * 256 + tid;
      int r = u >> 3;
      int d0 = (u & 7) * 8;
      size_t t = (size_t)b * 512 + kt * 64 + r;
      bf16x8 kv = *(const bf16x8*)(qkv + t * 2304 + 768 + h * 64 + d0);
      *(bf16x8*)&Ks[r][d0] = kv;
    }
    // V: transposed scalar staging
#pragma unroll
    for (int i = 0; i < 8; ++i) {
      int pi = i * 256 + tid;
      int r = pi >> 5, dp = pi & 31;
      size_t t = (size_t)b * 512 + kt * 64 + r;
      uint32_t uv = *(const uint32_t*)(qkv + t * 2304 + 1536 + h * 64 + dp * 2);
      *(ushort_t*)&Vt[dp * 2][r]     = (ushort_t)(uv & 0xffffu);
      *(ushort_t*)&Vt[dp * 2 + 1][r] = (ushort_t)(uv >> 16);
    }
    __syncthreads();

    f32x4 sacc[2][4];
#pragma unroll
    for (int mi = 0; mi < 2; ++mi)
#pragma unroll
      for (int ni = 0; ni < 4; ++ni) sacc[mi][ni] = (f32x4){0.f, 0.f, 0.f, 0.f};
    __builtin_amdgcn_s_setprio(1);
#pragma unroll
    for (int ni = 0; ni < 4; ++ni) {
      bf16x8 kb0 = *(const bf16x8*)&Ks[ni * 16 + lc][g * 8];
      bf16x8 kb1 = *(const bf16x8*)&Ks[ni * 16 + lc][32 + g * 8];
#pragma unroll
      for (int mi = 0; mi < 2; ++mi) {
        sacc[mi][ni] = __builtin_amdgcn_mfma_f32_16x16x32_bf16(qa[mi][0], kb0, sacc[mi][ni], 0, 0, 0);
        sacc[mi][ni] = __builtin_amdgcn_mfma_f32_16x16x32_bf16(qa[mi][1], kb1, sacc[mi][ni], 0, 0, 0);
      }
    }
    __builtin_amdgcn_s_setprio(0);
    if (kt >= 2 * qt) {
#pragma unroll
      for (int mi = 0; mi < 2; ++mi)
#pragma unroll
        for (int ni = 0; ni < 4; ++ni)
#pragma unroll
          for (int r = 0; r < 4; ++r) {
            int ql = w * 32 + mi * 16 + g * 4 + r;
            int kl = ni * 16 + lc;
            if (kt * 64 + kl > qt * 128 + ql) sacc[mi][ni][r] = -1e30f;
          }
    }
#pragma unroll
    for (int mi = 0; mi < 2; ++mi) {
      float mx[4], sm[4], mn[4], sc[4];
#pragma unroll
      for (int r = 0; r < 4; ++r)
        mx[r] = fmaxf(fmaxf(sacc[mi][0][r], sacc[mi][1][r]), fmaxf(sacc[mi][2][r], sacc[mi][3][r]));
#pragma unroll
      for (int d = 1; d < 16; d <<= 1)
#pragma unroll
        for (int r = 0; r < 4; ++r) mx[r] = fmaxf(mx[r], __shfl_xor(mx[r], d));
#pragma unroll
      for (int r = 0; r < 4; ++r) {
        mn[r] = fmaxf(m_r[mi][r], mx[r]);
        sc[r] = __expf(m_r[mi][r] - mn[r]);
        sm[r] = 0.f;
      }
#pragma unroll
      for (int ni = 0; ni < 4; ++ni)
#pragma unroll
        for (int r = 0; r < 4; ++r) {
          float p = __expf(sacc[mi][ni][r] - mn[r]);
          sacc[mi][ni][r] = p;
          sm[r] += p;
        }
#pragma unroll
      for (int d = 1; d < 16; d <<= 1)
#pragma unroll
        for (int r = 0; r < 4; ++r) sm[r] += __shfl_xor(sm[r], d);
#pragma unroll
      for (int r = 0; r < 4; ++r) {
        l_r[mi][r] = l_r[mi][r] * sc[r] + sm[r];
        m_r[mi][r] = mn[r];
      }
#pragma unroll
      for (int ni = 0; ni < 4; ++ni)
#pragma unroll
        for (int r = 0; r < 4; ++r) acc_o[mi][ni][r] *= sc[r];
#pragma unroll
      for (int ni = 0; ni < 4; ++ni)
#pragma unroll
        for (int r = 0; r < 4; ++r)
          *(ushort_t*)&Pl[w][mi * 16 + g * 4 + r][ni * 16 + lc] = f2bfu(sacc[mi][ni][r]);
    }
    __syncthreads();
    __builtin_amdgcn_s_setprio(1);
#pragma unroll
    for (int ks = 0; ks < 2; ++ks) {
      bf16x8 pa[2];
#pragma unroll
      for (int mi = 0; mi < 2; ++mi)
        pa[mi] = *(const bf16x8*)&Pl[w][mi * 16 + lc][ks * 32 + g * 8];
#pragma unroll
      for (int ni = 0; ni < 4; ++ni) {
        bf16x8 vb = *(const bf16x8*)&Vt[ni * 16 + lc][ks * 32 + g * 8];
#pragma unroll
        for (int mi = 0; mi < 2; ++mi)
          acc_o[mi][ni] = __builtin_amdgcn_mfma_f32_16x16x32_bf16(pa[mi], vb, acc_o[mi][ni], 0, 0, 0);
      }
    }
    __builtin_amdgcn_s_setprio(0);
  }
#pragma unroll
  for (int mi = 0; mi < 2; ++mi) {
    float inv[4];
#pragma unroll
    for (int r = 0; r < 4; ++r) inv[r] = 1.0f / l_r[mi][r];
#pragma unroll
    for (int ni = 0; ni < 4; ++ni)
#pragma unroll
      for (int r = 0; r < 4; ++r) {
        size_t t = (size_t)b * 512 + qt * 128 + w * 32 + mi * 16 + g * 4 + r;
        int d = ni * 16 + lc;
        out[t * 768 + h * 64 + d] = __float2bfloat16(acc_o[mi][ni][r] * inv[r]);
      }
  }
}

extern "C" void kernel_launch(void* const* d_in, const int* in_sizes, int n_in,
                              void* d_out, int out_size, void* d_ws, size_t ws_size,
                              hipStream_t stream) {
  const int*   ids    = (const int*)d_in[0];
  const float* embedW = (const float*)d_in[1];
  const float* norm1w = (const float*)d_in[2];
  const float* wq     = (const float*)d_in[3];
  const float* wk     = (const float*)d_in[4];
  const float* wv     = (const float*)d_in[5];
  const float* wo     = (const float*)d_in[6];
  const float* norm2w = (const float*)d_in[7];
  const float* wgate  = (const float*)d_in[8];
  const float* wval   = (const float*)d_in[9];
  const float* wout   = (const float*)d_in[10];
  const float* normfw = (const float*)d_in[11];
  const float* unemb  = (const float*)d_in[12];

  char* arena = (char*)d_out;
  size_t off = 0;
  auto alloc = [&](size_t bytes) -> char* {
    char* p = arena + off;
    off += (bytes + 255) & ~(size_t)255;
    return p;
  };
  float* x       = (float*)alloc(4096ull * 768 * 4);
  bf16*  h       = (bf16*)alloc(4096ull * 768 * 2);
  bf16*  qkv     = (bf16*)alloc(4096ull * 2304 * 2);
  bf16*  attnout = (bf16*)alloc(4096ull * 768 * 2);
  bf16*  act     = (bf16*)alloc(4096ull * 2048 * 2);
  bf16*  part    = (bf16*)alloc(4ull * 4096 * 768 * 2);
  float* cosT    = (float*)alloc(512 * 32 * 4);
  float* sinT    = (float*)alloc(512 * 32 * 4);
  bf16*  wqkvT   = (bf16*)alloc(6ull * 2304 * 768 * 2);
  bf16*  woT     = (bf16*)alloc(6ull * 768 * 768 * 2);
  bf16*  wgvT    = (bf16*)alloc(6ull * 4096 * 768 * 2);
  bf16*  woutT   = (bf16*)alloc(6ull * 768 * 2048 * 2);

  bf16* unembT = (bf16*)d_ws;
  bf16* hf     = (bf16*)((char*)d_ws + 32000ull * 768 * 2);

  prep_all_kernel<<<69632, 256, 0, stream>>>(ids, embedW, norm1w,
                                             wq, wk, wv, wo, wgate, wval, wout, unemb,
                                             cosT, sinT,
                                             wqkvT, woT, wgvT, woutT, unembT,
                                             x, h);

  for (int l = 0; l < 6; ++l) {
    gemm256<4><<<16 * 9, 512, 0, stream>>>(h, wqkvT + (size_t)l * 2304 * 768, qkv,
                                           4096, 2304, 768, cosT, sinT);
    attn_kernel<<<dim3(4, 12, 8), 256, 0, stream>>>(qkv, attnout);
    gemm_bt_sk<<<dim3(6, 32, 2), 256, 0, stream>>>(attnout, woT + (size_t)l * 768 * 768, part,
                                                   4096, 768, 384, 768);
    reduce_rms_kernel<2><<<4096, 256, 0, stream>>>(x, part, norm2w + (size_t)l * 768, h);
    gemm256<3><<<16 * 16, 512, 0, stream>>>(h, wgvT + (size_t)l * 4096 * 768, act,
                                            4096, 4096, 768, nullptr, nullptr);
    gemm_bt_sk<<<dim3(6, 32, 4), 256, 0, stream>>>(act, woutT + (size_t)l * 768 * 2048, part,
                                                   4096, 768, 512, 2048);
    if (l < 5)
      reduce_rms_kernel<4><<<4096, 256, 0, stream>>>(x, part, norm1w + (size_t)(l + 1) * 768, h);
    else
      reduce_rms_kernel<4><<<4096, 256, 0, stream>>>(x, part, normfw, hf);
  }

  gemm256<1><<<16 * 125, 512, 0, stream>>>(hf, unembT, (float*)d_out, 4096, 32000, 768,
                                           nullptr, nullptr);
}

// Round 14
// 1445.849 us; speedup vs baseline: 1.0019x; 1.0019x over previous
//
#include <hip/hip_runtime.h>
#include <hip/hip_bf16.h>
#include <stdint.h>

typedef __hip_bfloat16 bf16;
typedef unsigned short ushort_t;
typedef __attribute__((ext_vector_type(8))) short bf16x8;
typedef __attribute__((ext_vector_type(4))) float f32x4;

#define EPSV 1.1920929e-07f

__device__ __forceinline__ float bfu2f(uint32_t u) {
  union { uint32_t i; float f; } t; t.i = u << 16; return t.f;
}
__device__ __forceinline__ ushort_t f2bfu(float f) {
  bf16 h = __float2bfloat16(f);
  return *reinterpret_cast<ushort_t*>(&h);
}

#define BAR() __builtin_amdgcn_s_barrier()
#define SCHEDB() __builtin_amdgcn_sched_barrier(0)
#define WAIT_LGKM0() { asm volatile("s_waitcnt lgkmcnt(0)" ::: "memory"); SCHEDB(); }
#define WAIT_VM4() asm volatile("s_waitcnt vmcnt(4)" ::: "memory")
#define WAIT_VM0() asm volatile("s_waitcnt vmcnt(0)" ::: "memory")

// ---------------- prep_all: weight transposes + rope tables + embed+RMS ----------------
__global__ __launch_bounds__(256) void prep_all_kernel(
    const int* __restrict__ ids, const float* __restrict__ emb,
    const float* __restrict__ norm1w0,
    const float* __restrict__ wq, const float* __restrict__ wk,
    const float* __restrict__ wv, const float* __restrict__ wo,
    const float* __restrict__ wg, const float* __restrict__ wvl,
    const float* __restrict__ wout, const float* __restrict__ unemb,
    float* __restrict__ cosT, float* __restrict__ sinT,
    bf16* __restrict__ wqkvT, bf16* __restrict__ woT,
    bf16* __restrict__ wgvT, bf16* __restrict__ woutT,
    bf16* __restrict__ unembT,
    float* __restrict__ x, bf16* __restrict__ h) {
  int id = blockIdx.x;
  __shared__ float tl[32][33];
  __shared__ float red[4];

  if (id >= 65536) {
    const int row = id - 65536;
    const int tid = threadIdx.x;
    const float* er = emb + (size_t)ids[row] * 768;
    float v0 = er[tid], v1 = er[tid + 256], v2 = er[tid + 512];
    float s = v0 * v0 + v1 * v1 + v2 * v2;
#pragma unroll
    for (int d = 1; d < 64; d <<= 1) s += __shfl_xor(s, d);
    if ((tid & 63) == 0) red[tid >> 6] = s;
    __syncthreads();
    s = red[0] + red[1] + red[2] + red[3];
    float rs = rsqrtf(s * (1.0f / 768.0f) + EPSV);
    float* xr = x + (size_t)row * 768;
    bf16* hr = h + (size_t)row * 768;
    xr[tid] = v0; xr[tid + 256] = v1; xr[tid + 512] = v2;
    hr[tid]       = __float2bfloat16(v0 * rs * norm1w0[tid]);
    hr[tid + 256] = __float2bfloat16(v1 * rs * norm1w0[tid + 256]);
    hr[tid + 512] = __float2bfloat16(v2 * rs * norm1w0[tid + 512]);
    return;
  }
  if (id >= 65472) {
    int i = (id - 65472) * 256 + threadIdx.x;
    int c = i >> 5, dp = i & 31;
    float inv = powf(10000.0f, -(2.0f * dp) / 64.0f);
    float a = (float)c * inv;
    cosT[i] = cosf(a);
    sinT[i] = sinf(a);
    return;
  }

  const float* src; bf16* dst; int K, N, tile;
  bool gvmode = false; int w2 = 0;
  if (id < 13824) {
    int m = id / 576; tile = id % 576;
    int l = m >> 2, w3 = m & 3;
    K = 768; N = 768;
    const float* s0 = (w3 == 0) ? wq : (w3 == 1) ? wk : (w3 == 2) ? wv : wo;
    src = s0 + (size_t)l * 768 * 768;
    dst = (w3 < 3) ? wqkvT + (size_t)l * 2304 * 768 + (size_t)w3 * 768 * 768
                   : woT + (size_t)l * 768 * 768;
  } else if (id < 32256) {
    int id2 = id - 13824; int m = id2 / 1536; tile = id2 % 1536;
    int l = m >> 1; w2 = m & 1;
    K = 768; N = 2048; gvmode = true;
    src = (w2 ? wvl : wg) + (size_t)l * 768 * 2048;
    dst = wgvT + (size_t)l * 4096 * 768;
  } else if (id < 41472) {
    int id2 = id - 32256; int l = id2 / 1536; tile = id2 % 1536;
    K = 2048; N = 768;
    src = wout + (size_t)l * 2048 * 768;
    dst = woutT + (size_t)l * 768 * 2048;
  } else {
    tile = id - 41472;
    K = 768; N = 32000;
    src = unemb; dst = unembT;
  }
  int ntn = N >> 5;
  int nt = (tile % ntn) << 5, kt = (tile / ntn) << 5;
  int tx = threadIdx.x & 31, ty = threadIdx.x >> 5;
#pragma unroll
  for (int i = 0; i < 4; ++i)
    tl[ty + i * 8][tx] = src[(size_t)(kt + ty + i * 8) * N + nt + tx];
  __syncthreads();
#pragma unroll
  for (int i = 0; i < 4; ++i) {
    int n = nt + ty + i * 8;
    size_t nrow = gvmode ? (size_t)((n >> 7) * 256 + w2 * 128 + (n & 127)) : (size_t)n;
    dst[nrow * K + kt + tx] = __float2bfloat16(tl[tx][ty + i * 8]);
  }
}

// ---------------- fused split-K reduce (bf16 partials) + residual + RMSNorm ----------------
template <int S>
__global__ __launch_bounds__(256) void reduce_rms_kernel(float* __restrict__ x,
                                                         const bf16* __restrict__ P,
                                                         const float* __restrict__ wgt,
                                                         bf16* __restrict__ h) {
  const int row = blockIdx.x;
  const int tid = threadIdx.x;
  float* xr = x + (size_t)row * 768;
  const bool act2 = tid < 128;
  const int u0 = tid, u1 = tid + 256;

  float v00, v01, v10 = 0.f, v11 = 0.f;
  float s;
  {
    float2 xv = *(const float2*)(xr + 2 * u0);
    float a0 = xv.x, a1 = xv.y;
#pragma unroll
    for (int z = 0; z < S; ++z) {
      uint32_t pu = *(const uint32_t*)(P + ((size_t)z * 4096 + row) * 768 + 2 * u0);
      a0 += bfu2f(pu & 0xffffu); a1 += bfu2f(pu >> 16);
    }
    v00 = a0; v01 = a1;
    s = a0 * a0 + a1 * a1;
  }
  if (act2) {
    float2 xv = *(const float2*)(xr + 2 * u1);
    float a0 = xv.x, a1 = xv.y;
#pragma unroll
    for (int z = 0; z < S; ++z) {
      uint32_t pu = *(const uint32_t*)(P + ((size_t)z * 4096 + row) * 768 + 2 * u1);
      a0 += bfu2f(pu & 0xffffu); a1 += bfu2f(pu >> 16);
    }
    v10 = a0; v11 = a1;
    s += a0 * a0 + a1 * a1;
  }
#pragma unroll
  for (int d = 1; d < 64; d <<= 1) s += __shfl_xor(s, d);
  __shared__ float red[4];
  if ((tid & 63) == 0) red[tid >> 6] = s;
  __syncthreads();
  s = red[0] + red[1] + red[2] + red[3];
  float rs = rsqrtf(s * (1.0f / 768.0f) + EPSV);
  bf16* hr = h + (size_t)row * 768;
  {
    *(float2*)(xr + 2 * u0) = make_float2(v00, v01);
    uint32_t hw = (uint32_t)f2bfu(v00 * rs * wgt[2 * u0]) |
                  ((uint32_t)f2bfu(v01 * rs * wgt[2 * u0 + 1]) << 16);
    *(uint32_t*)(hr + 2 * u0) = hw;
  }
  if (act2) {
    *(float2*)(xr + 2 * u1) = make_float2(v10, v11);
    uint32_t hw = (uint32_t)f2bfu(v10 * rs * wgt[2 * u1]) |
                  ((uint32_t)f2bfu(v11 * rs * wgt[2 * u1 + 1]) << 16);
    *(uint32_t*)(hr + 2 * u1) = hw;
  }
}

// ---------------- 128^2 split-K GEMM: P[z][M][N](bf16) = A[:,zKS:(z+1)KS] * BT^T ----------------
__global__ __launch_bounds__(256) void gemm_bt_sk(const bf16* __restrict__ A,
                                                  const bf16* __restrict__ BT,
                                                  bf16* __restrict__ P,
                                                  int M, int N, int KS, int K) {
  __shared__ __align__(16) bf16 As[128 * 32];
  __shared__ __align__(16) bf16 Bs[128 * 32];
  const int tid = threadIdx.x;
  const int lane = tid & 63, w = tid >> 6;
  const int g = lane >> 4, lc = lane & 15;
  const int bm = blockIdx.y * 128, bn = blockIdx.x * 128;
  const int z = blockIdx.z;
  const int koff = z * KS;
  const int wm = (w >> 1) * 64, wn = (w & 1) * 64;

  f32x4 acc[4][4];
#pragma unroll
  for (int i = 0; i < 4; ++i)
#pragma unroll
    for (int j = 0; j < 4; ++j) acc[i][j] = (f32x4){0.f, 0.f, 0.f, 0.f};

  for (int k0 = koff; k0 < koff + KS; k0 += 32) {
    __syncthreads();
#pragma unroll
    for (int j = 0; j < 2; ++j) {
      int c = (w * 2 + j) * 64 + lane;
      int row = c >> 2, part = c & 3;
      const bf16* srcA = A + (size_t)(bm + row) * K + k0 + part * 8;
      const bf16* srcB = BT + (size_t)(bn + row) * K + k0 + part * 8;
      __builtin_amdgcn_global_load_lds((const __attribute__((address_space(1))) void*)srcA,
                                       (__attribute__((address_space(3))) void*)(As + (w * 2 + j) * 512),
                                       16, 0, 0);
      __builtin_amdgcn_global_load_lds((const __attribute__((address_space(1))) void*)srcB,
                                       (__attribute__((address_space(3))) void*)(Bs + (w * 2 + j) * 512),
                                       16, 0, 0);
    }
    __syncthreads();
    bf16x8 af[4], bfr[4];
#pragma unroll
    for (int mi = 0; mi < 4; ++mi)
      af[mi] = *(const bf16x8*)(As + (wm + mi * 16 + lc) * 32 + g * 8);
#pragma unroll
    for (int ni = 0; ni < 4; ++ni)
      bfr[ni] = *(const bf16x8*)(Bs + (wn + ni * 16 + lc) * 32 + g * 8);
#pragma unroll
    for (int mi = 0; mi < 4; ++mi)
#pragma unroll
      for (int ni = 0; ni < 4; ++ni)
        acc[mi][ni] = __builtin_amdgcn_mfma_f32_16x16x32_bf16(af[mi], bfr[ni], acc[mi][ni], 0, 0, 0);
  }

  bf16* Pz = P + (size_t)z * M * N;
#pragma unroll
  for (int mi = 0; mi < 4; ++mi)
#pragma unroll
    for (int ni = 0; ni < 4; ++ni)
#pragma unroll
      for (int r = 0; r < 4; ++r) {
        size_t row = (size_t)bm + wm + mi * 16 + g * 4 + r;
        size_t col = (size_t)bn + wn + ni * 16 + lc;
        Pz[row * N + col] = __float2bfloat16(acc[mi][ni][r]);
      }
}

// ---------------- 256^2 8-phase GEMM (T2+T3+T4+T5) ----------------
// MODE 0: store bf16 ; MODE 1: store f32 ; MODE 3: SWIGLU ; MODE 4: bf16 + RoPE
template <int MODE>
__global__ __launch_bounds__(512, 2) void gemm256(const bf16* __restrict__ A,
                                                  const bf16* __restrict__ BT,
                                                  void* __restrict__ C,
                                                  int M, int N, int K,
                                                  const float* __restrict__ cosT,
                                                  const float* __restrict__ sinT) {
  __shared__ __align__(16) bf16 lds[2][4][256 * 32];

  const int tid = threadIdx.x;
  const int lane = tid & 63, w = tid >> 6;
  const int wr = w >> 2, wc = w & 3;
  const int g = lane >> 4, lc = lane & 15;

  const int nwg = gridDim.x;
  const int q = nwg >> 3;
  const int wg = ((int)blockIdx.x & 7) * q + ((int)blockIdx.x >> 3);
  const int nby = M >> 8;
  const int bx = wg / nby, by = wg % nby;
  const int bm = by << 8, bn = bx << 8;

  const bf16* Ap = A + (size_t)bm * K;
  const bf16* Bp = BT + (size_t)bn * K;

  const int soff = (lc * 64) + ((((lane >> 4) ^ ((lane >> 1) & 3)) << 4));

  auto stage_half = [&](int buf, int slab, const bf16* Base, int kcol) {
#pragma unroll
    for (int j = 0; j < 2; ++j) {
      int half_id = w * 2 + j;
      int row = half_id * 16 + (lane >> 2);
      int s_log = (lane & 3) ^ ((lane >> 3) & 3);
      const bf16* src = Base + (size_t)row * K + kcol + s_log * 8;
      bf16* dst = &lds[buf][slab][half_id * 512];
      __builtin_amdgcn_global_load_lds((const __attribute__((address_space(1))) void*)src,
                                       (__attribute__((address_space(3))) void*)dst,
                                       16, 0, 0);
    }
  };

  f32x4 acc[8][4];
#pragma unroll
  for (int i = 0; i < 8; ++i)
#pragma unroll
    for (int j = 0; j < 4; ++j) acc[i][j] = (f32x4){0.f, 0.f, 0.f, 0.f};

  const int NT = K >> 6;

  stage_half(0, 0, Ap, 0);
  stage_half(0, 1, Bp, 0);
  stage_half(0, 2, Ap, 32);
  stage_half(0, 3, Bp, 32);

  bf16x8 aF[4], bF[4];

  auto ds_A = [&](int buf, int kk, int mh) {
#pragma unroll
    for (int i = 0; i < 4; ++i) {
      int byte = (wr * 128 + mh * 64 + i * 16) * 64 + soff;
      aF[i] = *(const bf16x8*)((const char*)&lds[buf][kk * 2][0] + byte);
    }
  };
  auto ds_B = [&](int buf, int kk) {
#pragma unroll
    for (int nf = 0; nf < 4; ++nf) {
      int rb = (MODE == 3) ? ((nf < 2) ? (wc * 32 + nf * 16) : (128 + wc * 32 + (nf - 2) * 16))
                           : (wc * 64 + nf * 16);
      int byte = rb * 64 + soff;
      bF[nf] = *(const bf16x8*)((const char*)&lds[buf][kk * 2 + 1][0] + byte);
    }
  };
  auto mfma16 = [&](int mh) {
    __builtin_amdgcn_s_setprio(1);
#pragma unroll
    for (int i = 0; i < 4; ++i)
#pragma unroll
      for (int nf = 0; nf < 4; ++nf)
        acc[mh * 4 + i][nf] =
            __builtin_amdgcn_mfma_f32_16x16x32_bf16(aF[i], bF[nf], acc[mh * 4 + i][nf], 0, 0, 0);
    __builtin_amdgcn_s_setprio(0);
  };

  for (int t = 0; t < NT; ++t) {
    const int buf = t & 1;
    const bool pf = (t + 1) < NT;
    const int knext = (t + 1) << 6;

    WAIT_VM4();
    BAR(); SCHEDB();
    if (pf) stage_half(buf ^ 1, 0, Ap, knext);
    ds_A(buf, 0, 0);
    ds_B(buf, 0);
    BAR();
    WAIT_LGKM0();
    mfma16(0);

    if (pf) stage_half(buf ^ 1, 1, Bp, knext);
    ds_A(buf, 0, 1);
    BAR();
    WAIT_LGKM0();
    mfma16(1);

    if (pf) { WAIT_VM4(); } else { WAIT_VM0(); }
    BAR(); SCHEDB();
    if (pf) stage_half(buf ^ 1, 2, Ap, knext + 32);
    ds_A(buf, 1, 0);
    ds_B(buf, 1);
    BAR();
    WAIT_LGKM0();
    mfma16(0);

    if (pf) stage_half(buf ^ 1, 3, Bp, knext + 32);
    ds_A(buf, 1, 1);
    BAR();
    WAIT_LGKM0();
    mfma16(1);
  }

  if (MODE == 3) {
    bf16* act = (bf16*)C;
#pragma unroll
    for (int mf = 0; mf < 8; ++mf)
#pragma unroll
      for (int nf = 0; nf < 2; ++nf)
#pragma unroll
        for (int r = 0; r < 4; ++r) {
          size_t row = (size_t)bm + wr * 128 + mf * 16 + g * 4 + r;
          size_t col = (size_t)(bn >> 1) + wc * 32 + nf * 16 + lc;
          float gg = acc[mf][nf][r];
          float vv = acc[mf][nf + 2][r];
          float sg = gg / (1.0f + __expf(-gg));
          act[row * 2048 + col] = __float2bfloat16(sg * vv);
        }
  } else if (MODE == 4) {
#pragma unroll
    for (int mf = 0; mf < 8; ++mf)
#pragma unroll
      for (int nf = 0; nf < 4; ++nf)
#pragma unroll
        for (int r = 0; r < 4; ++r) {
          int row = bm + wr * 128 + mf * 16 + g * 4 + r;
          int col = bn + wc * 64 + nf * 16 + lc;
          float v = acc[mf][nf][r];
          float p = __shfl_xor(v, 1);
          float outv = v;
          if (col < 1536) {
            int cpos = row & 511;
            int dp = (col & 63) >> 1;
            float cs = cosT[cpos * 32 + dp], sn = sinT[cpos * 32 + dp];
            float o = (col & 1) ? (p * sn + v * cs) : (v * cs - p * sn);
            outv = (col < 768) ? o * 0.125f : o;
          }
          ((bf16*)C)[(size_t)row * N + col] = __float2bfloat16(outv);
        }
  } else {
#pragma unroll
    for (int mf = 0; mf < 8; ++mf)
#pragma unroll
      for (int nf = 0; nf < 4; ++nf)
#pragma unroll
        for (int r = 0; r < 4; ++r) {
          size_t row = (size_t)bm + wr * 128 + mf * 16 + g * 4 + r;
          size_t col = (size_t)bn + wc * 64 + nf * 16 + lc;
          float v = acc[mf][nf][r];
          if (MODE == 0) ((bf16*)C)[row * N + col] = __float2bfloat16(v);
          else           ((float*)C)[row * N + col] = v;
        }
  }
}

// ---------------- fused causal flash attention (q,k pre-roped) ----------------
// Double-buffered K/V staging: stage tile kt+1 while computing tile kt.
// One barrier per k-tile (WAR protected by buffer parity; Pl is wave-private).
__global__ __launch_bounds__(256) void attn_kernel(const bf16* __restrict__ qkv,
                                                   bf16* __restrict__ out) {
  const int qt = 3 - blockIdx.x;
  const int h  = blockIdx.y;
  const int b  = blockIdx.z;
  const int tid = threadIdx.x;
  const int lane = tid & 63, w = tid >> 6;
  const int g = lane >> 4, lc = lane & 15;

  __shared__ __align__(16) bf16 Ks[2][64][72];
  __shared__ __align__(16) bf16 Vt[2][64][72];
  __shared__ __align__(16) bf16 Pl[4][32][72];

  bf16x8 qa[2][2];
#pragma unroll
  for (int mi = 0; mi < 2; ++mi)
#pragma unroll
    for (int ks = 0; ks < 2; ++ks) {
      size_t t = (size_t)b * 512 + qt * 128 + w * 32 + mi * 16 + lc;
      qa[mi][ks] = *(const bf16x8*)(qkv + t * 2304 + h * 64 + ks * 32 + g * 8);
    }

  float m_r[2][4], l_r[2][4];
  f32x4 acc_o[2][4];
#pragma unroll
  for (int mi = 0; mi < 2; ++mi)
#pragma unroll
    for (int r = 0; r < 4; ++r) { m_r[mi][r] = -1e30f; l_r[mi][r] = 0.f; }
#pragma unroll
  for (int mi = 0; mi < 2; ++mi)
#pragma unroll
    for (int ni = 0; ni < 4; ++ni) acc_o[mi][ni] = (f32x4){0.f, 0.f, 0.f, 0.f};

  const int nkt = 2 * qt + 2;

  auto stage = [&](int buf, int kt) {
    // K: vectorized 16B copy
#pragma unroll
    for (int j = 0; j < 2; ++j) {
      int u = j * 256 + tid;
      int r = u >> 3;
      int d0 = (u & 7) * 8;
      size_t t = (size_t)b * 512 + kt * 64 + r;
      bf16x8 kv = *(const bf16x8*)(qkv + t * 2304 + 768 + h * 64 + d0);
      *(bf16x8*)&Ks[buf][r][d0] = kv;
    }
    // V: transposed scalar staging
#pragma unroll
    for (int i = 0; i < 8; ++i) {
      int pi = i * 256 + tid;
      int r = pi >> 5, dp = pi & 31;
      size_t t = (size_t)b * 512 + kt * 64 + r;
      uint32_t uv = *(const uint32_t*)(qkv + t * 2304 + 1536 + h * 64 + dp * 2);
      *(ushort_t*)&Vt[buf][dp * 2][r]     = (ushort_t)(uv & 0xffffu);
      *(ushort_t*)&Vt[buf][dp * 2 + 1][r] = (ushort_t)(uv >> 16);
    }
  };

  stage(0, 0);

  for (int kt = 0; kt < nkt; ++kt) {
    const int buf = kt & 1;
    __syncthreads();   // stage(kt) visible; all waves done with PV(kt-1)
    if (kt + 1 < nkt) stage(buf ^ 1, kt + 1);   // overlaps with QK/softmax/PV below

    f32x4 sacc[2][4];
#pragma unroll
    for (int mi = 0; mi < 2; ++mi)
#pragma unroll
      for (int ni = 0; ni < 4; ++ni) sacc[mi][ni] = (f32x4){0.f, 0.f, 0.f, 0.f};
    __builtin_amdgcn_s_setprio(1);
#pragma unroll
    for (int ni = 0; ni < 4; ++ni) {
      bf16x8 kb0 = *(const bf16x8*)&Ks[buf][ni * 16 + lc][g * 8];
      bf16x8 kb1 = *(const bf16x8*)&Ks[buf][ni * 16 + lc][32 + g * 8];
#pragma unroll
      for (int mi = 0; mi < 2; ++mi) {
        sacc[mi][ni] = __builtin_amdgcn_mfma_f32_16x16x32_bf16(qa[mi][0], kb0, sacc[mi][ni], 0, 0, 0);
        sacc[mi][ni] = __builtin_amdgcn_mfma_f32_16x16x32_bf16(qa[mi][1], kb1, sacc[mi][ni], 0, 0, 0);
      }
    }
    __builtin_amdgcn_s_setprio(0);
    if (kt >= 2 * qt) {
#pragma unroll
      for (int mi = 0; mi < 2; ++mi)
#pragma unroll
        for (int ni = 0; ni < 4; ++ni)
#pragma unroll
          for (int r = 0; r < 4; ++r) {
            int ql = w * 32 + mi * 16 + g * 4 + r;
            int kl = ni * 16 + lc;
            if (kt * 64 + kl > qt * 128 + ql) sacc[mi][ni][r] = -1e30f;
          }
    }
#pragma unroll
    for (int mi = 0; mi < 2; ++mi) {
      float mx[4], sm[4], mn[4], sc[4];
#pragma unroll
      for (int r = 0; r < 4; ++r)
        mx[r] = fmaxf(fmaxf(sacc[mi][0][r], sacc[mi][1][r]), fmaxf(sacc[mi][2][r], sacc[mi][3][r]));
#pragma unroll
      for (int d = 1; d < 16; d <<= 1)
#pragma unroll
        for (int r = 0; r < 4; ++r) mx[r] = fmaxf(mx[r], __shfl_xor(mx[r], d));
#pragma unroll
      for (int r = 0; r < 4; ++r) {
        mn[r] = fmaxf(m_r[mi][r], mx[r]);
        sc[r] = __expf(m_r[mi][r] - mn[r]);
        sm[r] = 0.f;
      }
#pragma unroll
      for (int ni = 0; ni < 4; ++ni)
#pragma unroll
        for (int r = 0; r < 4; ++r) {
          float p = __expf(sacc[mi][ni][r] - mn[r]);
          sacc[mi][ni][r] = p;
          sm[r] += p;
        }
#pragma unroll
      for (int d = 1; d < 16; d <<= 1)
#pragma unroll
        for (int r = 0; r < 4; ++r) sm[r] += __shfl_xor(sm[r], d);
#pragma unroll
      for (int r = 0; r < 4; ++r) {
        l_r[mi][r] = l_r[mi][r] * sc[r] + sm[r];
        m_r[mi][r] = mn[r];
      }
#pragma unroll
      for (int ni = 0; ni < 4; ++ni)
#pragma unroll
        for (int r = 0; r < 4; ++r) acc_o[mi][ni][r] *= sc[r];
#pragma unroll
      for (int ni = 0; ni < 4; ++ni)
#pragma unroll
        for (int r = 0; r < 4; ++r)
          *(ushort_t*)&Pl[w][mi * 16 + g * 4 + r][ni * 16 + lc] = f2bfu(sacc[mi][ni][r]);
    }
    // Pl is wave-private: drain own LDS writes, no cross-wave barrier needed.
    WAIT_LGKM0();
    __builtin_amdgcn_s_setprio(1);
#pragma unroll
    for (int ks = 0; ks < 2; ++ks) {
      bf16x8 pa[2];
#pragma unroll
      for (int mi = 0; mi < 2; ++mi)
        pa[mi] = *(const bf16x8*)&Pl[w][mi * 16 + lc][ks * 32 + g * 8];
#pragma unroll
      for (int ni = 0; ni < 4; ++ni) {
        bf16x8 vb = *(const bf16x8*)&Vt[buf][ni * 16 + lc][ks * 32 + g * 8];
#pragma unroll
        for (int mi = 0; mi < 2; ++mi)
          acc_o[mi][ni] = __builtin_amdgcn_mfma_f32_16x16x32_bf16(pa[mi], vb, acc_o[mi][ni], 0, 0, 0);
      }
    }
    __builtin_amdgcn_s_setprio(0);
  }
#pragma unroll
  for (int mi = 0; mi < 2; ++mi) {
    float inv[4];
#pragma unroll
    for (int r = 0; r < 4; ++r) inv[r] = 1.0f / l_r[mi][r];
#pragma unroll
    for (int ni = 0; ni < 4; ++ni)
#pragma unroll
      for (int r = 0; r < 4; ++r) {
        size_t t = (size_t)b * 512 + qt * 128 + w * 32 + mi * 16 + g * 4 + r;
        int d = ni * 16 + lc;
        out[t * 768 + h * 64 + d] = __float2bfloat16(acc_o[mi][ni][r] * inv[r]);
      }
  }
}

extern "C" void kernel_launch(void* const* d_in, const int* in_sizes, int n_in,
                              void* d_out, int out_size, void* d_ws, size_t ws_size,
                              hipStream_t stream) {
  const int*   ids    = (const int*)d_in[0];
  const float* embedW = (const float*)d_in[1];
  const float* norm1w = (const float*)d_in[2];
  const float* wq     = (const float*)d_in[3];
  const float* wk     = (const float*)d_in[4];
  const float* wv     = (const float*)d_in[5];
  const float* wo     = (const float*)d_in[6];
  const float* norm2w = (const float*)d_in[7];
  const float* wgate  = (const float*)d_in[8];
  const float* wval   = (const float*)d_in[9];
  const float* wout   = (const float*)d_in[10];
  const float* normfw = (const float*)d_in[11];
  const float* unemb  = (const float*)d_in[12];

  char* arena = (char*)d_out;
  size_t off = 0;
  auto alloc = [&](size_t bytes) -> char* {
    char* p = arena + off;
    off += (bytes + 255) & ~(size_t)255;
    return p;
  };
  float* x       = (float*)alloc(4096ull * 768 * 4);
  bf16*  h       = (bf16*)alloc(4096ull * 768 * 2);
  bf16*  qkv     = (bf16*)alloc(4096ull * 2304 * 2);
  bf16*  attnout = (bf16*)alloc(4096ull * 768 * 2);
  bf16*  act     = (bf16*)alloc(4096ull * 2048 * 2);
  bf16*  part    = (bf16*)alloc(4ull * 4096 * 768 * 2);
  float* cosT    = (float*)alloc(512 * 32 * 4);
  float* sinT    = (float*)alloc(512 * 32 * 4);
  bf16*  wqkvT   = (bf16*)alloc(6ull * 2304 * 768 * 2);
  bf16*  woT     = (bf16*)alloc(6ull * 768 * 768 * 2);
  bf16*  wgvT    = (bf16*)alloc(6ull * 4096 * 768 * 2);
  bf16*  woutT   = (bf16*)alloc(6ull * 768 * 2048 * 2);

  bf16* unembT = (bf16*)d_ws;
  bf16* hf     = (bf16*)((char*)d_ws + 32000ull * 768 * 2);

  prep_all_kernel<<<69632, 256, 0, stream>>>(ids, embedW, norm1w,
                                             wq, wk, wv, wo, wgate, wval, wout, unemb,
                                             cosT, sinT,
                                             wqkvT, woT, wgvT, woutT, unembT,
                                             x, h);

  for (int l = 0; l < 6; ++l) {
    gemm256<4><<<16 * 9, 512, 0, stream>>>(h, wqkvT + (size_t)l * 2304 * 768, qkv,
                                           4096, 2304, 768, cosT, sinT);
    attn_kernel<<<dim3(4, 12, 8), 256, 0, stream>>>(qkv, attnout);
    gemm_bt_sk<<<dim3(6, 32, 2), 256, 0, stream>>>(attnout, woT + (size_t)l * 768 * 768, part,
                                                   4096, 768, 384, 768);
    reduce_rms_kernel<2><<<4096, 256, 0, stream>>>(x, part, norm2w + (size_t)l * 768, h);
    gemm256<3><<<16 * 16, 512, 0, stream>>>(h, wgvT + (size_t)l * 4096 * 768, act,
                                            4096, 4096, 768, nullptr, nullptr);
    gemm_bt_sk<<<dim3(6, 32, 4), 256, 0, stream>>>(act, woutT + (size_t)l * 768 * 2048, part,
                                                   4096, 768, 512, 2048);
    if (l < 5)
      reduce_rms_kernel<4><<<4096, 256, 0, stream>>>(x, part, norm1w + (size_t)(l + 1) * 768, h);
    else
      reduce_rms_kernel<4><<<4096, 256, 0, stream>>>(x, part, normfw, hf);
  }

  gemm256<1><<<16 * 125, 512, 0, stream>>>(hf, unembT, (float*)d_out, 4096, 32000, 768,
                                           nullptr, nullptr);
}